// Round 1
// baseline (7411.611 us; speedup 1.0000x reference)
//
#include <hip/hip_runtime.h>
#include <math.h>

// Sizes (compile-time constants for this problem)
// D_MODEL=1024, N_HEADS=16, D_HEAD=64, QLEN=512, MLEN=512, KLEN=1024, BATCH=8

// ---------------------------------------------------------------------------
// Generic fp32 GEMM: C[m,n] = sum_k A[m,k]*B[k,n] (+bias[n])
// AMODE: 0 = plain A[m*lda+k]; 1 = cat gather (m<4096 -> A(mem), else A2(inputs))
// BMODE: 0 = B[k*ldb+n];       1 = B^T stored as B[n*ldb+k]
// Tile 128x128, BK=16, 256 threads, 8x8 per thread.
// ---------------------------------------------------------------------------
template<int AMODE, int BMODE, bool BIAS>
__global__ __launch_bounds__(256) void gemm_f32(
    const float* __restrict__ A, const float* __restrict__ A2,
    const float* __restrict__ B, const float* __restrict__ bias,
    float* __restrict__ C, int M, int N, int K, int lda, int ldb, int ldc)
{
    __shared__ float As[16][132];
    __shared__ float Bs[16][132];
    int tid = threadIdx.x;
    int m0 = blockIdx.y * 128, n0 = blockIdx.x * 128;
    int tr = tid >> 4, tc = tid & 15;
    float acc[8][8] = {};

    for (int k0 = 0; k0 < K; k0 += 16) {
        // ---- stage A tile: As[kk][m]
        #pragma unroll
        for (int q = 0; q < 2; ++q) {
            int idx = tid * 2 + q;
            int m = idx >> 2, kq = (idx & 3) * 4;
            const float* src;
            if (AMODE == 1) {
                int gm = m0 + m;
                src = (gm < 4096) ? (A + (size_t)gm * lda + k0 + kq)
                                  : (A2 + (size_t)(gm - 4096) * lda + k0 + kq);
            } else {
                src = A + (size_t)(m0 + m) * lda + k0 + kq;
            }
            float4 v = *(const float4*)src;
            As[kq + 0][m] = v.x; As[kq + 1][m] = v.y;
            As[kq + 2][m] = v.z; As[kq + 3][m] = v.w;
        }
        // ---- stage B tile: Bs[kk][n]
        #pragma unroll
        for (int q = 0; q < 2; ++q) {
            int idx = tid * 2 + q;
            if (BMODE == 0) {
                int kk = idx >> 5, n = (idx & 31) * 4;
                float4 v = *(const float4*)(B + (size_t)(k0 + kk) * ldb + n0 + n);
                *(float4*)&Bs[kk][n] = v;
            } else {
                int n = idx >> 2, kq = (idx & 3) * 4;
                float4 v = *(const float4*)(B + (size_t)(n0 + n) * ldb + k0 + kq);
                Bs[kq + 0][n] = v.x; Bs[kq + 1][n] = v.y;
                Bs[kq + 2][n] = v.z; Bs[kq + 3][n] = v.w;
            }
        }
        __syncthreads();
        #pragma unroll
        for (int kk = 0; kk < 16; ++kk) {
            float a[8], bb[8];
            *(float4*)&a[0]  = *(float4*)&As[kk][tr * 8];
            *(float4*)&a[4]  = *(float4*)&As[kk][tr * 8 + 4];
            *(float4*)&bb[0] = *(float4*)&Bs[kk][tc * 8];
            *(float4*)&bb[4] = *(float4*)&Bs[kk][tc * 8 + 4];
            #pragma unroll
            for (int i = 0; i < 8; ++i)
                #pragma unroll
                for (int j = 0; j < 8; ++j)
                    acc[i][j] += a[i] * bb[j];
        }
        __syncthreads();
    }
    // ---- epilogue
    #pragma unroll
    for (int i = 0; i < 8; ++i) {
        size_t m = (size_t)m0 + tr * 8 + i;
        float* crow = C + m * ldc + n0 + tc * 8;
        #pragma unroll
        for (int j = 0; j < 8; j += 4) {
            float4 v;
            v.x = acc[i][j + 0]; v.y = acc[i][j + 1];
            v.z = acc[i][j + 2]; v.w = acc[i][j + 3];
            if (BIAS) {
                const float* bp = bias + n0 + tc * 8 + j;
                v.x += bp[0]; v.y += bp[1]; v.z += bp[2]; v.w += bp[3];
            }
            *(float4*)(crow + j) = v;
        }
    }
}

// ---------------------------------------------------------------------------
// Fused TXL attention. One block per (i-tile of 64 q rows, b, h).
// Online softmax over j-tiles of 64. BD uses a 128-row r_head_k window:
//   S[i,j] = (q+u)[i]·K[j] + (q+v)[i]·rk[j-i+511], masked for j > i+512.
// ---------------------------------------------------------------------------
__global__ __launch_bounds__(256) void attn_fused(
    const float* __restrict__ qkv, const float* __restrict__ rk,
    const float* __restrict__ u_, const float* __restrict__ v_,
    float* __restrict__ y1)
{
    __shared__ float qu[64][68], qv[64][68], Kt[64][68], Vt[64][68];
    __shared__ float RKs[128][68];
    __shared__ float S[64][68];
    __shared__ float mrow[64], lrow[64], scalef[64];
    __shared__ float pmax[64][16], psum[64][16];

    int tid = threadIdx.x;
    int it = blockIdx.x, b = blockIdx.y, h = blockIdx.z;
    int i0 = it * 64;
    int ti = tid >> 4, tj = tid & 15;

    // load q rows, build qu=q+u, qv=q+v
    {
        int r = tid >> 2, c0 = (tid & 3) * 16;
        size_t base = ((size_t)(i0 + r + 512) * 8 + b) * 3072 + h * 64;
        #pragma unroll
        for (int q = 0; q < 4; ++q) {
            int c = c0 + q * 4;
            float4 qq = *(const float4*)&qkv[base + c];
            float4 uu = *(const float4*)&u_[h * 64 + c];
            float4 vv = *(const float4*)&v_[h * 64 + c];
            *(float4*)&qu[r][c] = make_float4(qq.x + uu.x, qq.y + uu.y, qq.z + uu.z, qq.w + uu.w);
            *(float4*)&qv[r][c] = make_float4(qq.x + vv.x, qq.y + vv.y, qq.z + vv.z, qq.w + vv.w);
        }
    }
    if (tid < 64) { mrow[tid] = -1e30f; lrow[tid] = 0.f; }

    float Od[4][4] = {};
    int njt = it + 9;

    for (int jt = 0; jt < njt; ++jt) {
        int j0 = jt * 64;
        __syncthreads();   // guards q/m/l stores (iter 0) and prev-iter LDS reads
        // stage K, V tiles
        {
            int r = tid >> 2, c0 = (tid & 3) * 16;
            size_t kb = ((size_t)(j0 + r) * 8 + b) * 3072 + 1024 + h * 64;
            #pragma unroll
            for (int q = 0; q < 4; ++q) {
                int c = c0 + q * 4;
                *(float4*)&Kt[r][c] = *(const float4*)&qkv[kb + c];
                *(float4*)&Vt[r][c] = *(const float4*)&qkv[kb + 1024 + c];
            }
        }
        // stage r_head_k window: rows jj = j0-i0+448 + r2, clamped (invalid rows masked)
        {
            int r2 = tid >> 1, c0 = (tid & 1) * 32;
            int jj = j0 - i0 + 448 + r2;
            jj = jj < 0 ? 0 : (jj > 1023 ? 1023 : jj);
            size_t rb = (size_t)jj * 1024 + h * 64;
            #pragma unroll
            for (int q = 0; q < 8; ++q) {
                int c = c0 + q * 4;
                *(float4*)&RKs[r2][c] = *(const float4*)&rk[rb + c];
            }
        }
        __syncthreads();

        // ---- S tile compute (4x4 per thread)
        float acc[4][4] = {};
        int jlb = (tj - ti) * 4 + 60;   // local rk row base; +(j-i+3) per element
        #pragma unroll 4
        for (int d4 = 0; d4 < 64; d4 += 4) {
            float4 Aq[4], Cq[4], Kv[4], Rv[7];
            #pragma unroll
            for (int i = 0; i < 4; ++i) {
                Aq[i] = *(float4*)&qu[ti * 4 + i][d4];
                Cq[i] = *(float4*)&qv[ti * 4 + i][d4];
                Kv[i] = *(float4*)&Kt[tj * 4 + i][d4];
            }
            #pragma unroll
            for (int t = 0; t < 7; ++t)
                Rv[t] = *(float4*)&RKs[jlb + t][d4];
            #pragma unroll
            for (int i = 0; i < 4; ++i)
                #pragma unroll
                for (int j = 0; j < 4; ++j) {
                    float4 kk = Kv[j];
                    float4 rr = Rv[j - i + 3];
                    acc[i][j] += Aq[i].x * kk.x + Aq[i].y * kk.y + Aq[i].z * kk.z + Aq[i].w * kk.w
                               + Cq[i].x * rr.x + Cq[i].y * rr.y + Cq[i].z * rr.z + Cq[i].w * rr.w;
                }
        }
        // scale + causal mask + per-thread row maxes
        #pragma unroll
        for (int i = 0; i < 4; ++i) {
            int gi = i0 + ti * 4 + i;
            float mx = -1e30f;
            #pragma unroll
            for (int j = 0; j < 4; ++j) {
                int gj = j0 + tj * 4 + j;
                float vS = acc[i][j] * 0.125f;
                if (gj > gi + 512) vS = -1e30f;
                acc[i][j] = vS;
                mx = fmaxf(mx, vS);
            }
            pmax[ti * 4 + i][tj] = mx;
        }
        __syncthreads();
        if (tid < 64) {
            float mo = mrow[tid], mn = mo;
            #pragma unroll
            for (int t = 0; t < 16; ++t) mn = fmaxf(mn, pmax[tid][t]);
            mrow[tid] = mn;
            scalef[tid] = __expf(mo - mn);
        }
        __syncthreads();
        // P = exp(S-m), partial sums, O rescale
        #pragma unroll
        for (int i = 0; i < 4; ++i) {
            int ri = ti * 4 + i;
            float mn = mrow[ri];
            float4 pv;
            pv.x = __expf(acc[i][0] - mn);
            pv.y = __expf(acc[i][1] - mn);
            pv.z = __expf(acc[i][2] - mn);
            pv.w = __expf(acc[i][3] - mn);
            *(float4*)&S[ri][tj * 4] = pv;
            psum[ri][tj] = pv.x + pv.y + pv.z + pv.w;
            float scl = scalef[ri];
            #pragma unroll
            for (int j2 = 0; j2 < 4; ++j2) Od[i][j2] *= scl;
        }
        __syncthreads();
        if (tid < 64) {
            float s = 0.f;
            #pragma unroll
            for (int t = 0; t < 16; ++t) s += psum[tid][t];
            lrow[tid] = lrow[tid] * scalef[tid] + s;
        }
        // ---- PV accumulate
        #pragma unroll 4
        for (int jb = 0; jb < 64; jb += 4) {
            float4 p0 = *(float4*)&S[ti * 4 + 0][jb];
            float4 p1 = *(float4*)&S[ti * 4 + 1][jb];
            float4 p2 = *(float4*)&S[ti * 4 + 2][jb];
            float4 p3 = *(float4*)&S[ti * 4 + 3][jb];
            float4 v0 = *(float4*)&Vt[jb + 0][tj * 4];
            float4 v1 = *(float4*)&Vt[jb + 1][tj * 4];
            float4 v2 = *(float4*)&Vt[jb + 2][tj * 4];
            float4 v3 = *(float4*)&Vt[jb + 3][tj * 4];
            float4 pr[4] = {p0, p1, p2, p3};
            #pragma unroll
            for (int i = 0; i < 4; ++i) {
                Od[i][0] += pr[i].x * v0.x + pr[i].y * v1.x + pr[i].z * v2.x + pr[i].w * v3.x;
                Od[i][1] += pr[i].x * v0.y + pr[i].y * v1.y + pr[i].z * v2.y + pr[i].w * v3.y;
                Od[i][2] += pr[i].x * v0.z + pr[i].y * v1.z + pr[i].z * v2.z + pr[i].w * v3.z;
                Od[i][3] += pr[i].x * v0.w + pr[i].y * v1.w + pr[i].z * v2.w + pr[i].w * v3.w;
            }
        }
    }
    __syncthreads();
    // normalize + store: y1[(i*8+b)*1024 + h*64 + d]
    #pragma unroll
    for (int i = 0; i < 4; ++i) {
        int ri = ti * 4 + i;
        float inv = 1.f / lrow[ri];
        float4 o = make_float4(Od[i][0] * inv, Od[i][1] * inv, Od[i][2] * inv, Od[i][3] * inv);
        *(float4*)&y1[((size_t)(i0 + ri) * 8 + b) * 1024 + h * 64 + tj * 4] = o;
    }
}

// ---------------------------------------------------------------------------
// One GRU timestep. 64 blocks x 256 threads; block w owns d in [w*16, w*16+16).
// Thread (dd, kc): partial dots over k-slice [kc*64, kc*64+64) for 3 gates x 8 batches.
// ---------------------------------------------------------------------------
__global__ __launch_bounds__(256) void gru_step(
    const float* __restrict__ hin, float* __restrict__ hout,
    const float* __restrict__ Whh, const float* __restrict__ bhh,
    const float* __restrict__ xg, float* __restrict__ out, int step)
{
    __shared__ float hs[8192];        // h: [8][1024]
    __shared__ float red[24][256];    // [g*8+b][kc*16+dd]
    int tid = threadIdx.x;
    int w = blockIdx.x;

    #pragma unroll
    for (int q = 0; q < 8; ++q) {
        int i4 = q * 256 + tid;
        *(float4*)&hs[i4 * 4] = *(const float4*)&hin[i4 * 4];
    }
    __syncthreads();

    int dd = tid & 15, kc = tid >> 4;
    int d = w * 16 + dd;
    float acc0[8] = {}, acc1[8] = {}, acc2[8] = {};
    const float* w0 = Whh + (size_t)d * 1024 + kc * 64;
    const float* w1 = Whh + (size_t)(1024 + d) * 1024 + kc * 64;
    const float* w2 = Whh + (size_t)(2048 + d) * 1024 + kc * 64;
    #pragma unroll 4
    for (int k4 = 0; k4 < 64; k4 += 4) {
        float4 wr = *(const float4*)(w0 + k4);
        float4 wz = *(const float4*)(w1 + k4);
        float4 wn = *(const float4*)(w2 + k4);
        int kbase = kc * 64 + k4;
        #pragma unroll
        for (int b = 0; b < 8; ++b) {
            float4 h4 = *(const float4*)&hs[b * 1024 + kbase];
            acc0[b] += wr.x * h4.x + wr.y * h4.y + wr.z * h4.z + wr.w * h4.w;
            acc1[b] += wz.x * h4.x + wz.y * h4.y + wz.z * h4.z + wz.w * h4.w;
            acc2[b] += wn.x * h4.x + wn.y * h4.y + wn.z * h4.z + wn.w * h4.w;
        }
    }
    int c = kc * 16 + dd;
    #pragma unroll
    for (int b = 0; b < 8; ++b) {
        red[b][c]      = acc0[b];
        red[8 + b][c]  = acc1[b];
        red[16 + b][c] = acc2[b];
    }
    __syncthreads();

    if (tid < 128) {
        int b = tid >> 4, d2l = tid & 15;
        int d2 = w * 16 + d2l;
        float s0 = 0.f, s1 = 0.f, s2 = 0.f;
        #pragma unroll
        for (int k2 = 0; k2 < 16; ++k2) {
            s0 += red[b][k2 * 16 + d2l];
            s1 += red[8 + b][k2 * 16 + d2l];
            s2 += red[16 + b][k2 * 16 + d2l];
        }
        size_t xb = ((size_t)step * 8 + b) * 3072;
        float xr = xg[xb + d2];
        float xz = xg[xb + 1024 + d2];
        float xn = xg[xb + 2048 + d2];
        float r = 1.f / (1.f + __expf(-(xr + s0 + bhh[d2])));
        float z = 1.f / (1.f + __expf(-(xz + s1 + bhh[1024 + d2])));
        float n = tanhf(xn + r * (s2 + bhh[2048 + d2]));
        float hprev = hs[b * 1024 + d2];
        float hnew = (1.f - z) * n + z * hprev;
        hout[b * 1024 + d2] = hnew;
        out[((size_t)step * 8 + b) * 1024 + d2] = hnew;
    }
}

// ---------------------------------------------------------------------------
extern "C" void kernel_launch(void* const* d_in, const int* in_sizes, int n_in,
                              void* d_out, int out_size, void* d_ws, size_t ws_size,
                              hipStream_t stream) {
    (void)in_sizes; (void)n_in; (void)out_size; (void)ws_size;
    const float* inputs = (const float*)d_in[0];
    const float* r_in   = (const float*)d_in[1];
    const float* u_in   = (const float*)d_in[2];
    const float* v_in   = (const float*)d_in[3];
    const float* mem    = (const float*)d_in[4];
    const float* Wqkv   = (const float*)d_in[5];
    const float* Wr     = (const float*)d_in[6];
    const float* Wo     = (const float*)d_in[7];
    const float* Wih    = (const float*)d_in[8];
    const float* Whh    = (const float*)d_in[9];
    const float* bih    = (const float*)d_in[10];
    const float* bhh    = (const float*)d_in[11];
    const float* h0     = (const float*)d_in[12];
    float* out = (float*)d_out;
    float* ws = (float*)d_ws;

    float* qkv = ws;                    // 1024*8*3072 = 25165824
    float* rk  = ws + 25165824;         // 1024*1024   =  1048576
    float* y1  = ws + 26214400;         // 512*8*1024  =  4194304
    float* y2  = ws + 30408704;         // 512*8*1024  =  4194304
    float* xg  = ws + 34603008;         // 512*8*3072  = 12582912
    float* hA  = ws + 47185920;         // 8192
    float* hB  = hA + 8192;             // 8192

    dim3 blk(256);
    // qkv = [mem; inputs] @ W_qkv   (8192 x 3072, K=1024)
    gemm_f32<1, 0, false><<<dim3(24, 64), blk, 0, stream>>>(
        mem, inputs, Wqkv, nullptr, qkv, 8192, 3072, 1024, 1024, 3072, 3072);
    // rk = r @ W_r                   (1024 x 1024)
    gemm_f32<0, 0, false><<<dim3(8, 8), blk, 0, stream>>>(
        r_in, nullptr, Wr, nullptr, rk, 1024, 1024, 1024, 1024, 1024, 1024);
    // fused attention -> y1
    attn_fused<<<dim3(8, 8, 16), blk, 0, stream>>>(qkv, rk, u_in, v_in, y1);
    // y2 = y1 @ W_o                  (4096 x 1024)
    gemm_f32<0, 0, false><<<dim3(8, 32), blk, 0, stream>>>(
        y1, nullptr, Wo, nullptr, y2, 4096, 1024, 1024, 1024, 1024, 1024);
    // xg = y2 @ W_ih^T + b_ih        (4096 x 3072), B^T layout
    gemm_f32<0, 1, true><<<dim3(24, 32), blk, 0, stream>>>(
        y2, nullptr, Wih, bih, xg, 4096, 3072, 1024, 1024, 1024, 3072);
    // GRU recurrence: 512 steps
    const float* hin = h0;
    for (int s = 0; s < 512; ++s) {
        float* hp = (s & 1) ? hB : hA;
        gru_step<<<64, blk, 0, stream>>>(hin, hp, Whh, bhh, xg, out, s);
        hin = hp;
    }
}